// Round 1
// baseline (378.447 us; speedup 1.0000x reference)
//
#include <hip/hip_runtime.h>
#include <hip/hip_bf16.h>
#include <stdint.h>
#include <math.h>

// Problem constants (fixed by setup_inputs): B=1, S=2048, H=2048, nh=16, nkv=4, hd=128
#define SS 2048
#define HH 2048
#define NH 16
#define NKV 4
#define HD 128
#define HKV 512   // NKV*HD
#define NQKV 3072 // H + 2*HKV

typedef __bf16 bf16x8 __attribute__((ext_vector_type(8)));
typedef float f32x4 __attribute__((ext_vector_type(4)));

static_assert(sizeof(bf16x8) == 16, "bf16x8 must be 16B");

// async global->LDS, 16B per lane. LDS side must be lane-contiguous (wave-uniform
// base + lane*16) — all call sites below use c = chunk index linear in tid.
__device__ __forceinline__ void async_ld16(const void* gp, void* lp) {
  __builtin_amdgcn_global_load_lds(
      (const __attribute__((address_space(1))) unsigned int*)(uintptr_t)gp,
      (__attribute__((address_space(3))) unsigned int*)(uintptr_t)lp,
      16, 0, 0);
}

__device__ __forceinline__ unsigned short f2bu(float f) {
  __hip_bfloat16 b = __float2bfloat16(f);
  return *reinterpret_cast<unsigned short*>(&b);
}

// ---------------- fp32 -> bf16 convert (vectorized) ----------------
__global__ void k_cvt(const float4* __restrict__ src, ushort4* __restrict__ dst, int n4) {
  int i = blockIdx.x * 256 + threadIdx.x;
  if (i >= n4) return;
  float4 v = src[i];
  ushort4 o;
  o.x = f2bu(v.x); o.y = f2bu(v.y); o.z = f2bu(v.z); o.w = f2bu(v.w);
  dst[i] = o;
}

// ---------------- fp32 [R][C] (row stride sstride) -> bf16 [C][R] ----------------
__global__ void k_transpose(const float* __restrict__ src, __hip_bfloat16* __restrict__ dst,
                            int R, int C, int sstride) {
  __shared__ float tile[32][33];
  int bx = blockIdx.x * 32; // over C
  int by = blockIdx.y * 32; // over R
  int tx = threadIdx.x, ty = threadIdx.y; // (32,8)
#pragma unroll
  for (int i = 0; i < 4; i++)
    tile[ty + i * 8][tx] = src[(size_t)(by + ty + i * 8) * sstride + bx + tx];
  __syncthreads();
#pragma unroll
  for (int i = 0; i < 4; i++)
    dst[(size_t)(bx + ty + i * 8) * R + by + tx] = __float2bfloat16(tile[tx][ty + i * 8]);
}

// ---------------- bf16 GEMM: C[M,N] = A[M,K] * B[N,K]^T, fp32 out ----------------
// m97 pattern: 128x128 tile, BK=32, 4 waves 2x2, 4x4 16x16x32 mfma per wave.
__global__ __launch_bounds__(256) void k_gemm_bt(
    const __hip_bfloat16* __restrict__ A, const __hip_bfloat16* __restrict__ B,
    float* __restrict__ C, int M, int N, int K, int lda, int ldb, int ldc) {
  __shared__ __align__(16) __hip_bfloat16 sA[128 * 32];
  __shared__ __align__(16) __hip_bfloat16 sB[128 * 32];
  const int tid = threadIdx.x;
  const int lane = tid & 63;
  const int wave = tid >> 6;
  const int bm = blockIdx.y * 128;
  const int bn = blockIdx.x * 128;
  const int wm = (wave & 1) * 64;
  const int wn = (wave >> 1) * 64;
  const int am = lane & 15;
  const int ch = lane >> 4;

  f32x4 acc[4][4] = {};

  for (int k0 = 0; k0 < K; k0 += 32) {
#pragma unroll
    for (int q = 0; q < 2; q++) {
      int c = q * 256 + tid;          // 16B chunk id, 512 chunks per tile
      int row = c >> 2, col = (c & 3) * 8;
      async_ld16(A + (size_t)(bm + row) * lda + k0 + col, (char*)sA + c * 16);
      async_ld16(B + (size_t)(bn + row) * ldb + k0 + col, (char*)sB + c * 16);
    }
    __syncthreads();
    bf16x8 a[4], b[4];
#pragma unroll
    for (int i = 0; i < 4; i++) a[i] = *(const bf16x8*)(sA + (wm + i * 16 + am) * 32 + ch * 8);
#pragma unroll
    for (int j = 0; j < 4; j++) b[j] = *(const bf16x8*)(sB + (wn + j * 16 + am) * 32 + ch * 8);
#pragma unroll
    for (int i = 0; i < 4; i++)
#pragma unroll
      for (int j = 0; j < 4; j++)
        acc[i][j] = __builtin_amdgcn_mfma_f32_16x16x32_bf16(a[i], b[j], acc[i][j], 0, 0, 0);
    __syncthreads();
  }
#pragma unroll
  for (int i = 0; i < 4; i++)
#pragma unroll
    for (int j = 0; j < 4; j++)
#pragma unroll
      for (int r = 0; r < 4; r++) {
        int row = bm + wm + i * 16 + ch * 4 + r;
        int col = bn + wn + j * 16 + am;
        C[(size_t)row * ldc + col] = acc[i][j][r];
      }
}

// ---------------- RoPE (fp32 in, bf16 out) ----------------
__global__ void k_rope(const float* __restrict__ src, int sstride,
                       __hip_bfloat16* __restrict__ dst, int dstride,
                       const int* __restrict__ pos, int pairs, int nrows) {
  __shared__ float sFreq[64];
  if (threadIdx.x < 64)
    sFreq[threadIdx.x] = (float)(1.0 / pow(10000.0, (double)threadIdx.x / 64.0));
  __syncthreads();
  int idx = blockIdx.x * 256 + threadIdx.x;
  if (idx >= nrows * pairs) return;
  int s = idx / pairs;
  int p = idx - s * pairs;
  int i = p & 63;
  float ang = (float)pos[s] * sFreq[i];
  float sn, cs;
  sincosf(ang, &sn, &cs);
  const float2 v = *(const float2*)(src + (size_t)s * sstride + 2 * p);
  float o0 = v.x * cs - v.y * sn;
  float o1 = v.x * sn + v.y * cs;
  ushort2 o; o.x = f2bu(o0); o.y = f2bu(o1);
  *(ushort2*)(dst + (size_t)s * dstride + 2 * p) = o;
}

// ---------------- flash attention, causal + pad + segment ----------------
// grid (qt=16, h=16), block 256 (4 waves); wave w owns q rows [qt*128+w*32, +32)
__global__ __launch_bounds__(256, 1) void k_attn(
    const __hip_bfloat16* __restrict__ Qb,   // [S][H]
    const __hip_bfloat16* __restrict__ Kb,   // [S][HKV]
    const __hip_bfloat16* __restrict__ Vt,   // [HKV][S]
    const int* __restrict__ amv, const int* __restrict__ seg,
    __hip_bfloat16* __restrict__ O) {        // [S][H]
  const float SCL = 0.08838834764831845f * 1.4426950408889634f; // 1/sqrt(128) * log2(e)
  __shared__ __align__(16) __hip_bfloat16 sK[128 * 128];
  __shared__ __align__(16) __hip_bfloat16 sVt[128 * 128];
  __shared__ __align__(16) __hip_bfloat16 sP[4][32 * 144]; // stride 144 kills bank conflicts
  __shared__ int sKinfo[128];

  const int qt = blockIdx.x;
  const int h = blockIdx.y;
  const int kvh = h >> 2;
  const int tid = threadIdx.x, lane = tid & 63, w = tid >> 6;
  const int am = lane & 15, ch = lane >> 4;
  const int qrow_base = qt * 128 + w * 32;

  // Q fragments: loaded once, reused for every K tile
  bf16x8 qf[2][4];
#pragma unroll
  for (int it = 0; it < 2; it++)
#pragma unroll
    for (int ks = 0; ks < 4; ks++)
      qf[it][ks] = *(const bf16x8*)(Qb + (size_t)(qrow_base + it * 16 + am) * HH + h * HD + ks * 32 + ch * 8);

  int segq[2][4];
#pragma unroll
  for (int it = 0; it < 2; it++)
#pragma unroll
    for (int r = 0; r < 4; r++)
      segq[it][r] = seg[qrow_base + it * 16 + ch * 4 + r];

  f32x4 o_acc[2][8] = {};
  float m_s[2][4], l_s[2][4];
#pragma unroll
  for (int it = 0; it < 2; it++)
#pragma unroll
    for (int r = 0; r < 4; r++) { m_s[it][r] = -__builtin_inff(); l_s[it][r] = 0.f; }

  for (int kt = 0; kt <= qt; kt++) {
    // stage K tile [128 keys][128 d] and Vt tile [128 d][128 keys]
#pragma unroll
    for (int q = 0; q < 8; q++) {
      int c = q * 256 + tid; // 2048 chunks of 16B per 32KB tile
      int row = c >> 4, col = (c & 15) * 8;
      async_ld16(Kb + (size_t)(kt * 128 + row) * HKV + kvh * 128 + col, (char*)sK + c * 16);
      async_ld16(Vt + (size_t)(kvh * 128 + row) * SS + kt * 128 + col, (char*)sVt + c * 16);
    }
    if (tid < 128) {
      int kidx = kt * 128 + tid;
      sKinfo[tid] = (amv[kidx] > 0) ? seg[kidx] : 0x7fffffff;
    }
    __syncthreads();

    // S = Q K^T
    f32x4 sacc[2][8] = {};
#pragma unroll
    for (int ks = 0; ks < 4; ks++)
#pragma unroll
      for (int jt = 0; jt < 8; jt++) {
        bf16x8 kf = *(const bf16x8*)(sK + (jt * 16 + am) * 128 + ks * 32 + ch * 8);
        sacc[0][jt] = __builtin_amdgcn_mfma_f32_16x16x32_bf16(qf[0][ks], kf, sacc[0][jt], 0, 0, 0);
        sacc[1][jt] = __builtin_amdgcn_mfma_f32_16x16x32_bf16(qf[1][ks], kf, sacc[1][jt], 0, 0, 0);
      }

    // online softmax per row-tile
#pragma unroll
    for (int it = 0; it < 2; it++) {
      float rm[4] = {-__builtin_inff(), -__builtin_inff(), -__builtin_inff(), -__builtin_inff()};
#pragma unroll
      for (int jt = 0; jt < 8; jt++) {
        int kloc = jt * 16 + am;
        int kinfo = sKinfo[kloc];
#pragma unroll
        for (int r = 0; r < 4; r++) {
          int qrow = qrow_base + it * 16 + ch * 4 + r;
          float v = sacc[it][jt][r] * SCL;
          bool valid = (kinfo == segq[it][r]) && (kt * 128 + kloc <= qrow);
          v = valid ? v : -__builtin_inff();
          sacc[it][jt][r] = v;
          rm[r] = fmaxf(rm[r], v);
        }
      }
#pragma unroll
      for (int off = 1; off < 16; off <<= 1)
#pragma unroll
        for (int r = 0; r < 4; r++) rm[r] = fmaxf(rm[r], __shfl_xor(rm[r], off, 64));
      float alpha[4], rl[4];
#pragma unroll
      for (int r = 0; r < 4; r++) {
        float mn = fmaxf(m_s[it][r], rm[r]);
        alpha[r] = exp2f(m_s[it][r] - mn);
        m_s[it][r] = mn;
        rl[r] = 0.f;
      }
#pragma unroll
      for (int jt = 0; jt < 8; jt++)
#pragma unroll
        for (int r = 0; r < 4; r++) {
          float p = exp2f(sacc[it][jt][r] - m_s[it][r]);
          sacc[it][jt][r] = p;
          rl[r] += p;
        }
#pragma unroll
      for (int off = 1; off < 16; off <<= 1)
#pragma unroll
        for (int r = 0; r < 4; r++) rl[r] += __shfl_xor(rl[r], off, 64);
#pragma unroll
      for (int r = 0; r < 4; r++) l_s[it][r] = l_s[it][r] * alpha[r] + rl[r];
#pragma unroll
      for (int jt = 0; jt < 8; jt++)
#pragma unroll
        for (int r = 0; r < 4; r++) o_acc[it][jt][r] *= alpha[r];
      // P: C-layout -> LDS (A-layout round trip); sP is per-wave private
      __hip_bfloat16* pw = &sP[w][0];
#pragma unroll
      for (int jt = 0; jt < 8; jt++)
#pragma unroll
        for (int r = 0; r < 4; r++)
          pw[(it * 16 + ch * 4 + r) * 144 + jt * 16 + am] = __float2bfloat16(sacc[it][jt][r]);
    }

    // O += P V  (per-wave: M=32, N=128, K=128)
#pragma unroll
    for (int ks = 0; ks < 4; ks++) {
      bf16x8 vf[8];
#pragma unroll
      for (int jt = 0; jt < 8; jt++)
        vf[jt] = *(const bf16x8*)(sVt + (jt * 16 + am) * 128 + ks * 32 + ch * 8);
#pragma unroll
      for (int it = 0; it < 2; it++) {
        bf16x8 pf = *(const bf16x8*)(&sP[w][(it * 16 + am) * 144 + ks * 32 + ch * 8]);
#pragma unroll
        for (int jt = 0; jt < 8; jt++)
          o_acc[it][jt] = __builtin_amdgcn_mfma_f32_16x16x32_bf16(pf, vf[jt], o_acc[it][jt], 0, 0, 0);
      }
    }
    __syncthreads();
  }

  // normalize + store
#pragma unroll
  for (int it = 0; it < 2; it++) {
    float inv[4];
#pragma unroll
    for (int r = 0; r < 4; r++) inv[r] = 1.0f / l_s[it][r];
#pragma unroll
    for (int jt = 0; jt < 8; jt++)
#pragma unroll
      for (int r = 0; r < 4; r++) {
        int row = qrow_base + it * 16 + ch * 4 + r;
        O[(size_t)row * HH + h * HD + jt * 16 + am] = __float2bfloat16(o_acc[it][jt][r] * inv[r]);
      }
  }
}

extern "C" void kernel_launch(void* const* d_in, const int* in_sizes, int n_in,
                              void* d_out, int out_size, void* d_ws, size_t ws_size,
                              hipStream_t stream) {
  const float* X  = (const float*)d_in[0];
  const int* amv  = (const int*)d_in[1];
  const int* seg  = (const int*)d_in[2];
  const int* pos  = (const int*)d_in[3];
  const float* Wq = (const float*)d_in[4];
  const float* Wk = (const float*)d_in[5];
  const float* Wv = (const float*)d_in[6];
  const float* Wo = (const float*)d_in[7];
  float* out = (float*)d_out;

  // workspace carve-up (~73 MB). All sizes are 256B multiples -> weight blocks
  // WqT/WkT/WvT stay contiguous for the fused QKV GEMM.
  char* ws = (char*)d_ws;
  size_t off = 0;
  auto alloc = [&](size_t bytes) { void* p = ws + off; off += (bytes + 255) & ~(size_t)255; return p; };
  __hip_bfloat16* Xb   = (__hip_bfloat16*)alloc((size_t)SS * HH * 2);
  __hip_bfloat16* WqT  = (__hip_bfloat16*)alloc((size_t)HH * HH * 2);
  __hip_bfloat16* WkT  = (__hip_bfloat16*)alloc((size_t)HKV * HH * 2);
  __hip_bfloat16* WvT  = (__hip_bfloat16*)alloc((size_t)HKV * HH * 2);
  __hip_bfloat16* WoT  = (__hip_bfloat16*)alloc((size_t)HH * HH * 2);
  float*          QKV  = (float*)alloc((size_t)SS * NQKV * 4);
  __hip_bfloat16* Qb   = (__hip_bfloat16*)alloc((size_t)SS * HH * 2);
  __hip_bfloat16* Kb   = (__hip_bfloat16*)alloc((size_t)SS * HKV * 2);
  __hip_bfloat16* Vt   = (__hip_bfloat16*)alloc((size_t)HKV * SS * 2);
  __hip_bfloat16* Ab   = (__hip_bfloat16*)alloc((size_t)SS * HH * 2);
  (void)WkT; (void)WvT;

  // 1) X -> bf16
  k_cvt<<<(SS * HH / 4 + 255) / 256, 256, 0, stream>>>((const float4*)X, (ushort4*)Xb, SS * HH / 4);
  // 2) weights -> bf16, transposed to [N][K]
  k_transpose<<<dim3(HH / 32, HH / 32), dim3(32, 8), 0, stream>>>(Wq, WqT, HH, HH, HH);
  k_transpose<<<dim3(HKV / 32, HH / 32), dim3(32, 8), 0, stream>>>(Wk, WkT, HH, HKV, HKV);
  k_transpose<<<dim3(HKV / 32, HH / 32), dim3(32, 8), 0, stream>>>(Wv, WvT, HH, HKV, HKV);
  k_transpose<<<dim3(HH / 32, HH / 32), dim3(32, 8), 0, stream>>>(Wo, WoT, HH, HH, HH);
  // 3) fused QKV projection: [2048,3072] = Xb @ [WqT|WkT|WvT]^T
  k_gemm_bt<<<dim3(NQKV / 128, SS / 128), 256, 0, stream>>>(Xb, WqT, QKV, SS, NQKV, HH, HH, HH, NQKV);
  // 4) RoPE Q,K (fp32 -> bf16); V transpose-convert to [HKV][S]
  k_rope<<<(SS * (HH / 2) + 255) / 256, 256, 0, stream>>>(QKV, NQKV, Qb, HH, pos, HH / 2, SS);
  k_rope<<<(SS * (HKV / 2) + 255) / 256, 256, 0, stream>>>(QKV + HH, NQKV, Kb, HKV, pos, HKV / 2, SS);
  k_transpose<<<dim3(HKV / 32, SS / 32), dim3(32, 8), 0, stream>>>(QKV + HH + HKV, Vt, SS, HKV, NQKV);
  // 5) attention
  k_attn<<<dim3(SS / 128, NH), 256, 0, stream>>>(Qb, Kb, Vt, amv, seg, Ab);
  // 6) output projection
  k_gemm_bt<<<dim3(HH / 128, SS / 128), 256, 0, stream>>>(Ab, WoT, out, SS, HH, HH, HH, HH, HH);
}

// Round 2
// 309.362 us; speedup vs baseline: 1.2233x; 1.2233x over previous
//
#include <hip/hip_runtime.h>
#include <hip/hip_bf16.h>
#include <stdint.h>
#include <math.h>

// Problem constants (fixed by setup_inputs): B=1, S=2048, H=2048, nh=16, nkv=4, hd=128
#define SS 2048
#define HH 2048
#define NH 16
#define NKV 4
#define HD 128
#define HKV 512   // NKV*HD
#define NQKV 3072 // H + 2*HKV

typedef __bf16 bf16x8 __attribute__((ext_vector_type(8)));
typedef float f32x4 __attribute__((ext_vector_type(4)));

static_assert(sizeof(bf16x8) == 16, "bf16x8 must be 16B");

// async global->LDS, 16B per lane. LDS side must be lane-contiguous (wave-uniform
// base + lane*16); the GLOBAL side is per-lane, which is where we put the swizzle.
__device__ __forceinline__ void async_ld16(const void* gp, void* lp) {
  __builtin_amdgcn_global_load_lds(
      (const __attribute__((address_space(1))) unsigned int*)(uintptr_t)gp,
      (__attribute__((address_space(3))) unsigned int*)(uintptr_t)lp,
      16, 0, 0);
}

__device__ __forceinline__ unsigned short f2bu(float f) {
  __hip_bfloat16 b = __float2bfloat16(f);
  return *reinterpret_cast<unsigned short*>(&b);
}

// ---------------- fp32 -> bf16 convert (vectorized) ----------------
__global__ void k_cvt(const float4* __restrict__ src, ushort4* __restrict__ dst, int n4) {
  int i = blockIdx.x * 256 + threadIdx.x;
  if (i >= n4) return;
  float4 v = src[i];
  ushort4 o;
  o.x = f2bu(v.x); o.y = f2bu(v.y); o.z = f2bu(v.z); o.w = f2bu(v.w);
  dst[i] = o;
}

// ---------------- fp32 [R][C] (row stride sstride) -> bf16 [C][R] ----------------
__global__ void k_transpose(const float* __restrict__ src, __hip_bfloat16* __restrict__ dst,
                            int R, int C, int sstride) {
  __shared__ float tile[32][33];
  int bx = blockIdx.x * 32; // over C
  int by = blockIdx.y * 32; // over R
  int tx = threadIdx.x, ty = threadIdx.y; // (32,8)
#pragma unroll
  for (int i = 0; i < 4; i++)
    tile[ty + i * 8][tx] = src[(size_t)(by + ty + i * 8) * sstride + bx + tx];
  __syncthreads();
#pragma unroll
  for (int i = 0; i < 4; i++)
    dst[(size_t)(bx + ty + i * 8) * R + by + tx] = __float2bfloat16(tile[tx][ty + i * 8]);
}

// ---------------- bf16 [R][C] (row stride sstride) -> bf16 [C][R] ----------------
__global__ void k_transpose_bf(const __hip_bfloat16* __restrict__ src, __hip_bfloat16* __restrict__ dst,
                               int R, int C, int sstride) {
  __shared__ __hip_bfloat16 tile[32][33];
  int bx = blockIdx.x * 32; // over C
  int by = blockIdx.y * 32; // over R
  int tx = threadIdx.x, ty = threadIdx.y; // (32,8)
#pragma unroll
  for (int i = 0; i < 4; i++)
    tile[ty + i * 8][tx] = src[(size_t)(by + ty + i * 8) * sstride + bx + tx];
  __syncthreads();
#pragma unroll
  for (int i = 0; i < 4; i++)
    dst[(size_t)(bx + ty + i * 8) * R + by + tx] = tile[tx][ty + i * 8];
}

// ---------------- bf16 GEMM: C[M,N] = A[M,K] * B[N,K]^T ----------------
// m97 pattern: 128x128 tile, BK=32, 4 waves 2x2, 4x4 16x16x32 mfma per wave.
// LDS chunks XOR-swizzled by (row>>1)&3 so fragment ds_read_b128 is 2-way (free).
__device__ __forceinline__ void cstore(float* p, float v) { *p = v; }
__device__ __forceinline__ void cstore(__hip_bfloat16* p, float v) { *p = __float2bfloat16(v); }

template <typename OutT>
__global__ __launch_bounds__(256) void k_gemm_bt(
    const __hip_bfloat16* __restrict__ A, const __hip_bfloat16* __restrict__ B,
    OutT* __restrict__ C, int M, int N, int K, int lda, int ldb, int ldc) {
  __shared__ __align__(16) __hip_bfloat16 sA[128 * 32];
  __shared__ __align__(16) __hip_bfloat16 sB[128 * 32];
  const int tid = threadIdx.x;
  const int lane = tid & 63;
  const int wave = tid >> 6;
  const int bm = blockIdx.y * 128;
  const int bn = blockIdx.x * 128;
  const int wm = (wave & 1) * 64;
  const int wn = (wave >> 1) * 64;
  const int am = lane & 15;
  const int ch = lane >> 4;

  f32x4 acc[4][4] = {};

  for (int k0 = 0; k0 < K; k0 += 32) {
#pragma unroll
    for (int q = 0; q < 2; q++) {
      int c = q * 256 + tid;          // 16B chunk id, 512 chunks per tile
      int row = c >> 2, kp = c & 3;
      int col = (kp ^ ((row >> 1) & 3)) * 8; // logical element offset for phys chunk kp
      async_ld16(A + (size_t)(bm + row) * lda + k0 + col, (char*)sA + c * 16);
      async_ld16(B + (size_t)(bn + row) * ldb + k0 + col, (char*)sB + c * 16);
    }
    __syncthreads();
    bf16x8 a[4], b[4];
#pragma unroll
    for (int i = 0; i < 4; i++) {
      int row = wm + i * 16 + am;
      a[i] = *(const bf16x8*)(sA + row * 32 + ((ch ^ ((row >> 1) & 3)) * 8));
    }
#pragma unroll
    for (int j = 0; j < 4; j++) {
      int row = wn + j * 16 + am;
      b[j] = *(const bf16x8*)(sB + row * 32 + ((ch ^ ((row >> 1) & 3)) * 8));
    }
#pragma unroll
    for (int i = 0; i < 4; i++)
#pragma unroll
      for (int j = 0; j < 4; j++)
        acc[i][j] = __builtin_amdgcn_mfma_f32_16x16x32_bf16(a[i], b[j], acc[i][j], 0, 0, 0);
    __syncthreads();
  }
#pragma unroll
  for (int i = 0; i < 4; i++)
#pragma unroll
    for (int j = 0; j < 4; j++)
#pragma unroll
      for (int r = 0; r < 4; r++) {
        int row = bm + wm + i * 16 + ch * 4 + r;
        int col = bn + wn + j * 16 + am;
        cstore(C + (size_t)row * ldc + col, acc[i][j][r]);
      }
}

// ---------------- RoPE (bf16 in, bf16 out) ----------------
__global__ void k_rope(const __hip_bfloat16* __restrict__ src, int sstride,
                       __hip_bfloat16* __restrict__ dst, int dstride,
                       const int* __restrict__ pos, int pairs, int nrows) {
  __shared__ float sFreq[64];
  if (threadIdx.x < 64)
    sFreq[threadIdx.x] = (float)(1.0 / pow(10000.0, (double)threadIdx.x / 64.0));
  __syncthreads();
  int idx = blockIdx.x * 256 + threadIdx.x;
  if (idx >= nrows * pairs) return;
  int s = idx / pairs;
  int p = idx - s * pairs;
  int i = p & 63;
  float ang = (float)pos[s] * sFreq[i];
  float sn, cs;
  sincosf(ang, &sn, &cs);
  const ushort2 v = *(const ushort2*)(src + (size_t)s * sstride + 2 * p);
  float x0 = __bfloat162float(*(const __hip_bfloat16*)&v.x);
  float x1 = __bfloat162float(*(const __hip_bfloat16*)&v.y);
  float o0 = x0 * cs - x1 * sn;
  float o1 = x0 * sn + x1 * cs;
  ushort2 o; o.x = f2bu(o0); o.y = f2bu(o1);
  *(ushort2*)(dst + (size_t)s * dstride + 2 * p) = o;
}

// ---------------- flash attention, causal + pad + segment ----------------
// grid 512 blocks (32 q-tiles of 64 rows x 16 heads), block 256 = 4 waves,
// wave w owns 16 q rows. LDS 66KB -> 2 blocks/CU. K/V tiles XOR-swizzled
// (chunk ^= row&15) so all ds_read_b128 are 2-way (free). P is round-tripped
// through the (already-consumed) sK region to keep LDS under 80KB.
// Block id mapping pairs qt with 31-qt so co-resident blocks have equal work.
__global__ __launch_bounds__(256, 2) void k_attn(
    const __hip_bfloat16* __restrict__ Qb,   // [S][H]
    const __hip_bfloat16* __restrict__ Kb,   // [S][HKV]
    const __hip_bfloat16* __restrict__ Vt,   // [HKV][S]
    const int* __restrict__ amv, const int* __restrict__ seg,
    __hip_bfloat16* __restrict__ O) {        // [S][H]
  const float SCL = 0.08838834764831845f * 1.4426950408889634f; // 1/sqrt(128) * log2(e)
  __shared__ __align__(16) __hip_bfloat16 sK[128 * 128];   // 32KB; first 16KB doubles as sP
  __shared__ __align__(16) __hip_bfloat16 sVt[128 * 128];  // 32KB
  __shared__ int sKinfo[128];

  const int id = blockIdx.x;
  const int a0 = id & 255;
  const int h = a0 >> 4;
  const int qh = a0 & 15;
  const int qt = (id >> 8) ? (31 - qh) : qh;   // 64-row q-tile index 0..31
  const int kvh = h >> 2;
  const int tid = threadIdx.x, lane = tid & 63, w = tid >> 6;
  const int am = lane & 15, ch = lane >> 4;
  const int qrow0 = qt * 64 + w * 16;          // wave's 16 q rows
  __hip_bfloat16* sP = sK + w * (16 * 128);    // per-wave 4KB slice

  // Q fragments (A-layout): loaded once from global, reused every K tile
  bf16x8 qf[4];
#pragma unroll
  for (int ks = 0; ks < 4; ks++)
    qf[ks] = *(const bf16x8*)(Qb + (size_t)(qrow0 + am) * HH + h * HD + ks * 32 + ch * 8);

  int segq[4];
#pragma unroll
  for (int r = 0; r < 4; r++) segq[r] = seg[qrow0 + ch * 4 + r];

  f32x4 o_acc[8] = {};
  float m_s[4], l_s[4];
#pragma unroll
  for (int r = 0; r < 4; r++) { m_s[r] = -__builtin_inff(); l_s[r] = 0.f; }

  const int kt_max = qt >> 1;
  for (int kt = 0; kt <= kt_max; kt++) {
    // stage K tile [128 keys][128 d] and Vt tile [128 d][128 keys], swizzled
#pragma unroll
    for (int q = 0; q < 8; q++) {
      int c = q * 256 + tid; // 2048 chunks of 16B per 32KB tile
      int row = c >> 4, kp = c & 15;
      int col = (kp ^ (row & 15)) * 8;
      async_ld16(Kb + (size_t)(kt * 128 + row) * HKV + kvh * 128 + col, (char*)sK + c * 16);
      async_ld16(Vt + (size_t)(kvh * 128 + row) * SS + kt * 128 + col, (char*)sVt + c * 16);
    }
    if (tid < 128) {
      int kidx = kt * 128 + tid;
      sKinfo[tid] = (amv[kidx] > 0) ? seg[kidx] : 0x7fffffff;
    }
    __syncthreads();

    // S = Q K^T
    f32x4 sacc[8] = {};
#pragma unroll
    for (int ks = 0; ks < 4; ks++)
#pragma unroll
      for (int jt = 0; jt < 8; jt++) {
        bf16x8 kf = *(const bf16x8*)(sK + (jt * 16 + am) * 128 + (((ks * 4 + ch) ^ am) * 8));
        sacc[jt] = __builtin_amdgcn_mfma_f32_16x16x32_bf16(qf[ks], kf, sacc[jt], 0, 0, 0);
      }

    // mask + online softmax
    float rm[4] = {-__builtin_inff(), -__builtin_inff(), -__builtin_inff(), -__builtin_inff()};
#pragma unroll
    for (int jt = 0; jt < 8; jt++) {
      int kloc = jt * 16 + am;
      int kinfo = sKinfo[kloc];
#pragma unroll
      for (int r = 0; r < 4; r++) {
        int qrow = qrow0 + ch * 4 + r;
        float v = sacc[jt][r] * SCL;
        bool valid = (kinfo == segq[r]) && (kt * 128 + kloc <= qrow);
        v = valid ? v : -__builtin_inff();
        sacc[jt][r] = v;
        rm[r] = fmaxf(rm[r], v);
      }
    }
#pragma unroll
    for (int off = 1; off < 16; off <<= 1)
#pragma unroll
      for (int r = 0; r < 4; r++) rm[r] = fmaxf(rm[r], __shfl_xor(rm[r], off, 64));
    float alpha[4], rl[4];
#pragma unroll
    for (int r = 0; r < 4; r++) {
      float mn = fmaxf(m_s[r], rm[r]);
      alpha[r] = exp2f(m_s[r] - mn);
      m_s[r] = mn;
      rl[r] = 0.f;
    }
#pragma unroll
    for (int jt = 0; jt < 8; jt++)
#pragma unroll
      for (int r = 0; r < 4; r++) {
        float p = exp2f(sacc[jt][r] - m_s[r]);
        sacc[jt][r] = p;
        rl[r] += p;
      }
#pragma unroll
    for (int off = 1; off < 16; off <<= 1)
#pragma unroll
      for (int r = 0; r < 4; r++) rl[r] += __shfl_xor(rl[r], off, 64);
#pragma unroll
    for (int r = 0; r < 4; r++) l_s[r] = l_s[r] * alpha[r] + rl[r];
#pragma unroll
    for (int jt = 0; jt < 8; jt++)
#pragma unroll
      for (int r = 0; r < 4; r++) o_acc[jt][r] *= alpha[r];

    __syncthreads();   // all waves finished reading sK; safe to overwrite with P

    // P: C-layout -> own swizzled sP slice (aliases sK region)
#pragma unroll
    for (int jt = 0; jt < 8; jt++)
#pragma unroll
      for (int r = 0; r < 4; r++) {
        int row = ch * 4 + r;
        int chunk = (jt * 2 + (am >> 3)) ^ row;
        *(__hip_bfloat16*)((char*)sP + row * 256 + chunk * 16 + (am & 7) * 2) =
            __float2bfloat16(sacc[jt][r]);
      }

    // O += P V  (per-wave: M=16, N=128, K=128)
#pragma unroll
    for (int ks = 0; ks < 4; ks++) {
      bf16x8 pf = *(const bf16x8*)((const char*)sP + am * 256 + (((ks * 4 + ch) ^ am) * 16));
#pragma unroll
      for (int jt = 0; jt < 8; jt++) {
        bf16x8 vf = *(const bf16x8*)(sVt + (jt * 16 + am) * 128 + (((ks * 4 + ch) ^ am) * 8));
        o_acc[jt] = __builtin_amdgcn_mfma_f32_16x16x32_bf16(pf, vf, o_acc[jt], 0, 0, 0);
      }
    }
    __syncthreads();   // before next tile's staging overwrites sK/sVt
  }

  // normalize + store
  float inv[4];
#pragma unroll
  for (int r = 0; r < 4; r++) inv[r] = 1.0f / l_s[r];
#pragma unroll
  for (int jt = 0; jt < 8; jt++)
#pragma unroll
    for (int r = 0; r < 4; r++) {
      int row = qrow0 + ch * 4 + r;
      O[(size_t)row * HH + h * HD + jt * 16 + am] = __float2bfloat16(o_acc[jt][r] * inv[r]);
    }
}

extern "C" void kernel_launch(void* const* d_in, const int* in_sizes, int n_in,
                              void* d_out, int out_size, void* d_ws, size_t ws_size,
                              hipStream_t stream) {
  const float* X  = (const float*)d_in[0];
  const int* amv  = (const int*)d_in[1];
  const int* seg  = (const int*)d_in[2];
  const int* pos  = (const int*)d_in[3];
  const float* Wq = (const float*)d_in[4];
  const float* Wk = (const float*)d_in[5];
  const float* Wv = (const float*)d_in[6];
  const float* Wo = (const float*)d_in[7];
  float* out = (float*)d_out;

  // workspace carve-up (~60 MB); WqT/WkT/WvT contiguous for the fused QKV GEMM.
  char* ws = (char*)d_ws;
  size_t off = 0;
  auto alloc = [&](size_t bytes) { void* p = ws + off; off += (bytes + 255) & ~(size_t)255; return p; };
  __hip_bfloat16* Xb   = (__hip_bfloat16*)alloc((size_t)SS * HH * 2);
  __hip_bfloat16* WqT  = (__hip_bfloat16*)alloc((size_t)HH * HH * 2);
  __hip_bfloat16* WkT  = (__hip_bfloat16*)alloc((size_t)HKV * HH * 2);
  __hip_bfloat16* WvT  = (__hip_bfloat16*)alloc((size_t)HKV * HH * 2);
  __hip_bfloat16* WoT  = (__hip_bfloat16*)alloc((size_t)HH * HH * 2);
  __hip_bfloat16* QKVb = (__hip_bfloat16*)alloc((size_t)SS * NQKV * 2);
  __hip_bfloat16* Qb   = (__hip_bfloat16*)alloc((size_t)SS * HH * 2);
  __hip_bfloat16* Kb   = (__hip_bfloat16*)alloc((size_t)SS * HKV * 2);
  __hip_bfloat16* Vt   = (__hip_bfloat16*)alloc((size_t)HKV * SS * 2);
  __hip_bfloat16* Ab   = (__hip_bfloat16*)alloc((size_t)SS * HH * 2);
  (void)WkT; (void)WvT;

  // 1) X -> bf16
  k_cvt<<<(SS * HH / 4 + 255) / 256, 256, 0, stream>>>((const float4*)X, (ushort4*)Xb, SS * HH / 4);
  // 2) weights -> bf16, transposed to [N][K]
  k_transpose<<<dim3(HH / 32, HH / 32), dim3(32, 8), 0, stream>>>(Wq, WqT, HH, HH, HH);
  k_transpose<<<dim3(HKV / 32, HH / 32), dim3(32, 8), 0, stream>>>(Wk, WkT, HH, HKV, HKV);
  k_transpose<<<dim3(HKV / 32, HH / 32), dim3(32, 8), 0, stream>>>(Wv, WvT, HH, HKV, HKV);
  k_transpose<<<dim3(HH / 32, HH / 32), dim3(32, 8), 0, stream>>>(Wo, WoT, HH, HH, HH);
  // 3) fused QKV projection (bf16 out): [2048,3072] = Xb @ [WqT|WkT|WvT]^T
  k_gemm_bt<__hip_bfloat16><<<dim3(NQKV / 128, SS / 128), 256, 0, stream>>>(
      Xb, WqT, QKVb, SS, NQKV, HH, HH, HH, NQKV);
  // 4) RoPE Q,K; V transpose to [HKV][S]
  k_rope<<<(SS * (HH / 2) + 255) / 256, 256, 0, stream>>>(QKVb, NQKV, Qb, HH, pos, HH / 2, SS);
  k_rope<<<(SS * (HKV / 2) + 255) / 256, 256, 0, stream>>>(QKVb + HH, NQKV, Kb, HKV, pos, HKV / 2, SS);
  k_transpose_bf<<<dim3(HKV / 32, SS / 32), dim3(32, 8), 0, stream>>>(QKVb + HH + HKV, Vt, SS, HKV, NQKV);
  // 5) attention (512 balanced blocks)
  k_attn<<<dim3(512), 256, 0, stream>>>(Qb, Kb, Vt, amv, seg, Ab);
  // 6) output projection (fp32 out)
  k_gemm_bt<float><<<dim3(HH / 128, SS / 128), 256, 0, stream>>>(Ab, WoT, out, SS, HH, HH, HH, HH, HH);
}